// Round 14
// baseline (510.787 us; speedup 1.0000x reference)
//
#include <hip/hip_runtime.h>

#define NW 30000
#define ND 8192
#define DIM 300
#define DIM2 150
#define NNZA 600000
#define NNZX 524288
#define PD 320            // padded feature stride (bf16 elems)
#define PD_U 160          // padded stride in uint (2 bf16 each)
#define NBA 30            // cdiv(NW,1024)
#define NBX 8             // cdiv(ND,1024)
#define BN_SCALE 0.99999500003749971f

typedef unsigned int uint;
typedef unsigned short ushort;
typedef __attribute__((ext_vector_type(8))) short bf16x8;
typedef __attribute__((ext_vector_type(4))) float f32x4;
typedef __attribute__((ext_vector_type(4))) uint uint4v;

static inline int cdiv(int a, int b){ return (a + b - 1) / b; }

__device__ __forceinline__ float b2f_lo(uint u){ return __builtin_bit_cast(float, u << 16); }
__device__ __forceinline__ float b2f_hi(uint u){ return __builtin_bit_cast(float, u & 0xffff0000u); }
__device__ __forceinline__ ushort f2b(float f){
  uint u = __builtin_bit_cast(uint, f);
  u += 0x7fffu + ((u >> 16) & 1u);
  return (ushort)(u >> 16);
}
__device__ __forceinline__ uint packb(float x, float y){
  return (uint)f2b(x) | ((uint)f2b(y) << 16);
}

// ---------------- CSR build (A and X fused via blockIdx.y) ----------------
__global__ void k_hist2(const int* __restrict__ ra, const int* __restrict__ rx,
                        int* __restrict__ cntA, int* __restrict__ cntX){
  int i = blockIdx.x * blockDim.x + threadIdx.x;
  if (blockIdx.y == 0){
    if (i < NNZA) atomicAdd(&cntA[ra[i]], 1);
  } else {
    if (i < NNZX) atomicAdd(&cntX[rx[i]], 1);
  }
}

__global__ __launch_bounds__(1024) void k_bsum2(const int* __restrict__ cntA, const int* __restrict__ cntX,
                                                int* __restrict__ bsA, int* __restrict__ bsX){
  __shared__ int sd[1024];
  const int* cnt; int n; int* bs;
  if (blockIdx.y == 0){ cnt = cntA; n = NW; bs = bsA; }
  else                { cnt = cntX; n = ND; bs = bsX; }
  int t = threadIdx.x;
  int i = blockIdx.x * 1024 + t;
  sd[t] = (i < n) ? cnt[i] : 0;
  __syncthreads();
  #pragma unroll
  for (int o = 512; o > 0; o >>= 1){
    if (t < o) sd[t] += sd[t + o];
    __syncthreads();
  }
  if (t == 0) bs[blockIdx.x] = sd[0];
}

// one block, 128 threads: wave 0 scans A block-sums, wave 1 scans X block-sums
__global__ __launch_bounds__(128) void k_scan_small2(int* __restrict__ bsA, int* __restrict__ bsX,
                                                     int* __restrict__ a_rp, int* __restrict__ x_rp){
  int w = threadIdx.x >> 6, lane = threadIdx.x & 63;
  int* bs = w ? bsX : bsA;
  int nb  = w ? NBX : NBA;
  int* rp = w ? x_rp : a_rp;
  int n   = w ? ND : NW;
  int orig = (lane < nb) ? bs[lane] : 0;
  int v = orig;
  #pragma unroll
  for (int o = 1; o < 64; o <<= 1){
    int x = __shfl_up(v, o);
    if (lane >= o) v += x;
  }
  if (lane < nb) bs[lane] = v - orig;
  if (lane == nb - 1) rp[n] = v;
}

// per-block scan + offset; writes BOTH rp and the scatter cursor
__global__ __launch_bounds__(1024) void k_scan_apply2(const int* __restrict__ cntA, const int* __restrict__ cntX,
        const int* __restrict__ bsA, const int* __restrict__ bsX,
        int* __restrict__ a_rp, int* __restrict__ x_rp,
        int* __restrict__ curA, int* __restrict__ curX){
  __shared__ int sd[1024];
  const int* cnt; const int* bs; int n; int* rp; int* cur;
  if (blockIdx.y == 0){ cnt = cntA; bs = bsA; n = NW; rp = a_rp; cur = curA; }
  else                { cnt = cntX; bs = bsX; n = ND; rp = x_rp; cur = curX; }
  int t = threadIdx.x;
  int i = blockIdx.x * 1024 + t;
  int v = (i < n) ? cnt[i] : 0;
  sd[t] = v;
  __syncthreads();
  for (int o = 1; o < 1024; o <<= 1){
    int x = (t >= o) ? sd[t - o] : 0;
    __syncthreads();
    sd[t] += x;
    __syncthreads();
  }
  if (i < n){
    int start = bs[blockIdx.x] + sd[t] - v;
    rp[i] = start;
    cur[i] = start;
  }
}

// ---- range-split scatter: only rows in [lo,hi) handled; active write region ~2.3MB
// ---- stays L2-resident -> CSR lines evicted once fully-dirty, not 8x partial.
__global__ __launch_bounds__(256) void k_scat2(const int* __restrict__ a_rows, const int* __restrict__ a_cols,
        const float* __restrict__ a_vals, const int* __restrict__ x_rows, const int* __restrict__ x_cols,
        const float* __restrict__ x_vals, int* __restrict__ curA, int* __restrict__ curX,
        int* __restrict__ a_iv, int* __restrict__ x_iv, int aLo, int aHi, int xLo, int xHi){
  int gi = blockIdx.x * blockDim.x + threadIdx.x;
  if (blockIdx.y == 0){
    const int S = (NNZA + 3) >> 2;            // 150000
    if (gi >= S) return;
    #pragma unroll
    for (int k = 0; k < 4; ++k){
      int i = gi + k * S;
      if (i < NNZA){
        int r = a_rows[i];
        if (r >= aLo && r < aHi){
          int p = atomicAdd(&curA[r], 1);
          a_iv[2 * p]     = a_cols[i];
          a_iv[2 * p + 1] = __builtin_bit_cast(int, a_vals[i]);
        }
      }
    }
  } else {
    const int S = NNZX >> 2;                  // 131072
    if (gi >= S) return;
    #pragma unroll
    for (int k = 0; k < 4; ++k){
      int i = gi + k * S;
      int r = x_rows[i];
      if (r >= xLo && r < xHi){
        int p = atomicAdd(&curX[r], 1);
        x_iv[2 * p]     = x_cols[i];
        x_iv[2 * p + 1] = __builtin_bit_cast(int, x_vals[i]);
      }
    }
  }
}

// ---- fused prep: emb convert + 5 weight converts (scatters moved to k_scat2) ----
__global__ void k_prep(const float* __restrict__ emb, ushort* __restrict__ embb,
                       const float* __restrict__ w1, const float* __restrict__ w2, const float* __restrict__ w3,
                       const float* __restrict__ mw1, const float* __restrict__ mw2,
                       ushort* __restrict__ w1b, ushort* __restrict__ w2b, ushort* __restrict__ w3b,
                       ushort* __restrict__ mw1b, ushort* __restrict__ mw2b){
  int y = blockIdx.y;
  int gi = blockIdx.x * blockDim.x + threadIdx.x;
  if (y == 0){
    if (gi < NW * 40){
      int r = gi / 40;
      int c = (gi - r * 40) << 3;
      float x[8];
      #pragma unroll
      for (int j = 0; j < 8; ++j)
        x[j] = (c + j < DIM) ? emb[(size_t)r * DIM + c + j] : 0.f;
      uint4v o;
      o.x = packb(x[0], x[1]); o.y = packb(x[2], x[3]);
      o.z = packb(x[4], x[5]); o.w = packb(x[6], x[7]);
      *(uint4v*)(embb + (size_t)r * PD + c) = o;
    }
  } else {
    if (gi < PD * 40){
      int r = gi / 40;
      int c = (gi - r * 40) << 3;
      const float* src; ushort* dst; int srows;
      if      (y == 1){ src = w1;  dst = w1b;  srows = DIM;  }
      else if (y == 2){ src = w2;  dst = w2b;  srows = DIM;  }
      else if (y == 3){ src = w3;  dst = w3b;  srows = DIM;  }
      else if (y == 4){ src = mw1; dst = mw1b; srows = DIM;  }
      else            { src = mw2; dst = mw2b; srows = DIM2; }
      float x[8];
      #pragma unroll
      for (int j = 0; j < 8; ++j)
        x[j] = (r < srows && c + j < DIM) ? src[(size_t)r * DIM + c + j] : 0.f;
      uint4v o;
      o.x = packb(x[0], x[1]); o.y = packb(x[2], x[3]);
      o.z = packb(x[4], x[5]); o.w = packb(x[6], x[7]);
      *(uint4v*)(dst + (size_t)r * PD + c) = o;
    }
  }
}

// ---------------- SpMM over bf16 table: one wave per row, unroll-4, interleaved iv ------------
__global__ __launch_bounds__(256) void k_spmm_b(const int* __restrict__ rp, const int* __restrict__ iv,
        const uint* __restrict__ Hb, uint* __restrict__ Ob, int nrows){
  int wid = (blockIdx.x * blockDim.x + threadIdx.x) >> 6;
  int lane = threadIdx.x & 63;
  if (wid >= nrows) return;
  int s = rp[wid], e = rp[wid + 1];
  const bool half = lane < 32;
  float acc[4][6] = {};
  int k = s;
  for (; k + 4 <= e; k += 4){
    #pragma unroll
    for (int j = 0; j < 4; ++j){
      int c   = iv[2 * (k + j)];
      float v = __builtin_bit_cast(float, iv[2 * (k + j) + 1]);
      const uint* p = Hb + (size_t)c * PD_U;
      uint u0 = p[lane], u1 = p[lane + 64];
      uint u2 = half ? p[lane + 128] : 0;
      acc[j][0] = fmaf(v, b2f_lo(u0), acc[j][0]);
      acc[j][1] = fmaf(v, b2f_hi(u0), acc[j][1]);
      acc[j][2] = fmaf(v, b2f_lo(u1), acc[j][2]);
      acc[j][3] = fmaf(v, b2f_hi(u1), acc[j][3]);
      acc[j][4] = fmaf(v, b2f_lo(u2), acc[j][4]);
      acc[j][5] = fmaf(v, b2f_hi(u2), acc[j][5]);
    }
  }
  for (; k < e; ++k){
    int c   = iv[2 * k];
    float v = __builtin_bit_cast(float, iv[2 * k + 1]);
    const uint* p = Hb + (size_t)c * PD_U;
    uint u0 = p[lane], u1 = p[lane + 64];
    uint u2 = half ? p[lane + 128] : 0;
    acc[0][0] = fmaf(v, b2f_lo(u0), acc[0][0]);
    acc[0][1] = fmaf(v, b2f_hi(u0), acc[0][1]);
    acc[0][2] = fmaf(v, b2f_lo(u1), acc[0][2]);
    acc[0][3] = fmaf(v, b2f_hi(u1), acc[0][3]);
    acc[0][4] = fmaf(v, b2f_lo(u2), acc[0][4]);
    acc[0][5] = fmaf(v, b2f_hi(u2), acc[0][5]);
  }
  #pragma unroll
  for (int d = 0; d < 6; ++d)
    acc[0][d] += (acc[1][d] + acc[2][d]) + acc[3][d];
  uint* o = Ob + (size_t)wid * PD_U;
  o[lane] = packb(acc[0][0], acc[0][1]);
  o[lane + 64] = packb(acc[0][2], acc[0][3]);
  if (half) o[lane + 128] = packb(acc[0][4], acc[0][5]);
}

// ---------------- MFMA GEMM: C[M,Nvalid] = act(A[M,320]bf16 @ B[n][k]bf16^T) (proven) ------
// BM=128, BN=160, BK=64, 4 waves (2x2), wave tile 64x80 (4x5 16x16 frags).
__global__ __launch_bounds__(256) void k_mgemm(const ushort* __restrict__ A, const ushort* __restrict__ B,
        const float* __restrict__ bias, const float* __restrict__ bng, const float* __restrict__ bnb,
        ushort* __restrict__ C, int M, int Nvalid, int ldc, int relu){
  __shared__ ushort As[128][72];
  __shared__ ushort Bs[160][72];
  const int t = threadIdx.x;
  const int wid = t >> 6, lane = t & 63;
  const int bm = blockIdx.y << 7;
  const int bn = blockIdx.x * 160;
  const int wm = (wid >> 1) << 6;   // 0 / 64
  const int wn = (wid & 1) * 80;    // 0 / 80
  const int r16 = lane & 15;
  const int h8 = (lane >> 4) << 3;  // k-offset within 32
  f32x4 acc[4][5] = {};
  for (int k0 = 0; k0 < PD; k0 += 64){
    #pragma unroll
    for (int i = 0; i < 4; ++i){
      int q = t + (i << 8);
      int r = q >> 3, c = (q & 7) << 3;
      int gm = bm + r; if (gm >= M) gm = M - 1;
      *(bf16x8*)(&As[r][c]) = *(const bf16x8*)(A + (size_t)gm * PD + k0 + c);
    }
    #pragma unroll
    for (int i = 0; i < 5; ++i){
      int q = t + (i << 8);
      int r = q >> 3, c = (q & 7) << 3;
      *(bf16x8*)(&Bs[r][c]) = *(const bf16x8*)(B + (size_t)(bn + r) * PD + k0 + c);
    }
    __syncthreads();
    #pragma unroll
    for (int kk = 0; kk < 2; ++kk){
      bf16x8 af[4], bfr[5];
      #pragma unroll
      for (int m = 0; m < 4; ++m)
        af[m] = *(const bf16x8*)(&As[wm + m * 16 + r16][kk * 32 + h8]);
      #pragma unroll
      for (int n = 0; n < 5; ++n)
        bfr[n] = *(const bf16x8*)(&Bs[wn + n * 16 + r16][kk * 32 + h8]);
      #pragma unroll
      for (int m = 0; m < 4; ++m)
        #pragma unroll
        for (int n = 0; n < 5; ++n)
          acc[m][n] = __builtin_amdgcn_mfma_f32_16x16x32_bf16(af[m], bfr[n], acc[m][n], 0, 0, 0);
    }
    __syncthreads();
  }
  const int cr = (lane >> 4) << 2;
  #pragma unroll
  for (int m = 0; m < 4; ++m){
    #pragma unroll
    for (int n = 0; n < 5; ++n){
      int col = bn + wn + n * 16 + r16;
      #pragma unroll
      for (int j = 0; j < 4; ++j){
        int row = bm + wm + m * 16 + cr + j;
        if (row >= M) continue;
        float v = acc[m][n][j];
        if (col < Nvalid){
          if (bias) v += bias[col];
          if (bng)  v = v * (bng[col] * BN_SCALE) + bnb[col];
          if (relu) v = fmaxf(v, 0.f);
        } else v = 0.f;
        C[(size_t)row * ldc + col] = f2b(v);
      }
    }
  }
}

// ---------------- residual + LayerNorm; S = LN(0.3*emb + 0.7*H) + emb (bf16 emb input) ------
__global__ __launch_bounds__(256) void k_res_ln(const uint* __restrict__ E, const uint* __restrict__ Hb,
        const float* __restrict__ g, const float* __restrict__ bb, uint* __restrict__ S){
  int row = blockIdx.x * 4 + (threadIdx.x >> 6);
  int lane = threadIdx.x & 63;
  if (row >= NW) return;
  const uint* e = E + (size_t)row * PD_U;
  const uint* h = Hb + (size_t)row * PD_U;
  float x[6], ev[6];
  float sum = 0.f, sq = 0.f;
  #pragma unroll
  for (int j = 0; j < 3; ++j){
    int i = lane + j * 64;
    float e0 = 0.f, e1 = 0.f, h0 = 0.f, h1 = 0.f;
    if (i < 150){
      uint u = h[i];
      uint ue = e[i];
      h0 = b2f_lo(u);  h1 = b2f_hi(u);
      e0 = b2f_lo(ue); e1 = b2f_hi(ue);
    }
    float v0 = 0.3f * e0 + 0.7f * h0;
    float v1 = 0.3f * e1 + 0.7f * h1;
    if (i >= 150){ v0 = 0.f; v1 = 0.f; }
    x[2*j] = v0; x[2*j+1] = v1; ev[2*j] = e0; ev[2*j+1] = e1;
    sum += v0 + v1; sq += v0 * v0 + v1 * v1;
  }
  #pragma unroll
  for (int o = 32; o > 0; o >>= 1){ sum += __shfl_down(sum, o); sq += __shfl_down(sq, o); }
  sum = __shfl(sum, 0); sq = __shfl(sq, 0);
  const float inv = 1.f / (float)DIM;
  float mu = sum * inv;
  float var = sq * inv - mu * mu;
  float rs = rsqrtf(var + 1e-5f);
  uint* o = S + (size_t)row * PD_U;
  #pragma unroll
  for (int j = 0; j < 3; ++j){
    int i = lane + j * 64;
    if (i >= PD_U) continue;
    uint w = 0;
    if (i < 150){
      float r0 = (x[2*j]   - mu) * rs * g[2*i]   + bb[2*i]   + ev[2*j];
      float r1 = (x[2*j+1] - mu) * rs * g[2*i+1] + bb[2*i+1] + ev[2*j+1];
      w = packb(r0, r1);
    }
    o[i] = w;
  }
}

// ---------------- classifier: wave per row; 64 lanes cover 75 uints (11 lanes take 2) -------
__global__ __launch_bounds__(256) void k_clf(const uint* __restrict__ h2, const float* __restrict__ w,
                      const float* __restrict__ bias, float* __restrict__ out){
  int row = blockIdx.x * 4 + (threadIdx.x >> 6);
  int lane = threadIdx.x & 63;
  if (row >= ND) return;
  float s0, s1;
  {
    uint u = h2[(size_t)row * 80 + lane];       // uints 0..63 (cols 0..127)
    float h0 = b2f_lo(u), h1 = b2f_hi(u);
    int k = 2 * lane;
    s0 = h0 * w[k] + h1 * w[k + 1];
    s1 = h0 * w[DIM2 + k] + h1 * w[DIM2 + k + 1];
  }
  if (lane < 11){
    uint u = h2[(size_t)row * 80 + 64 + lane];  // uints 64..74 (cols 128..149)
    float h0 = b2f_lo(u), h1 = b2f_hi(u);
    int k = 2 * (64 + lane);
    s0 += h0 * w[k] + h1 * w[k + 1];
    s1 += h0 * w[DIM2 + k] + h1 * w[DIM2 + k + 1];
  }
  #pragma unroll
  for (int o = 32; o > 0; o >>= 1){
    s0 += __shfl_down(s0, o);
    s1 += __shfl_down(s1, o);
  }
  if (lane == 0){
    out[row * 2]     = s0 + bias[0];
    out[row * 2 + 1] = s1 + bias[1];
  }
}

extern "C" void kernel_launch(void* const* d_in, const int* in_sizes, int n_in,
                              void* d_out, int out_size, void* d_ws, size_t ws_size,
                              hipStream_t stream){
  const int*   a_rows = (const int*)  d_in[0];
  const int*   a_cols = (const int*)  d_in[1];
  const float* a_vals = (const float*)d_in[2];
  const int*   x_rows = (const int*)  d_in[3];
  const int*   x_cols = (const int*)  d_in[4];
  const float* x_vals = (const float*)d_in[5];
  const float* emb    = (const float*)d_in[6];
  const float* w1     = (const float*)d_in[7];
  const float* w2     = (const float*)d_in[8];
  const float* w3     = (const float*)d_in[9];
  const float* ln_g   = (const float*)d_in[10];
  const float* ln_b   = (const float*)d_in[11];
  const float* m_w1   = (const float*)d_in[12];
  const float* m_b1   = (const float*)d_in[13];
  const float* bn1_g  = (const float*)d_in[14];
  const float* bn1_b  = (const float*)d_in[15];
  const float* m_w2   = (const float*)d_in[16];
  const float* m_b2   = (const float*)d_in[17];
  const float* bn2_g  = (const float*)d_in[18];
  const float* bn2_b  = (const float*)d_in[19];
  const float* clf_w  = (const float*)d_in[20];
  const float* clf_b  = (const float*)d_in[21];
  float* out = (float*)d_out;

  char* ws = (char*)d_ws;
  size_t off = 0;
  auto take = [&](size_t nbytes)->void*{
    void* p = ws + off;
    off += (nbytes + 255) & ~(size_t)255;
    return p;
  };
  int*    a_rp   = (int*)   take((NW + 1) * 4);
  int*    a_iv   = (int*)   take((size_t)NNZA * 8);
  int*    x_rp   = (int*)   take((ND + 1) * 4);
  int*    x_iv   = (int*)   take((size_t)NNZX * 8);
  int*    cursors= (int*)   take((size_t)(NW + ND) * 4);
  int*    bsA    = (int*)   take(64 * 4);
  int*    bsX    = (int*)   take(64 * 4);
  ushort* embb   = (ushort*)take((size_t)NW * PD * 2);
  ushort* Tb     = (ushort*)take((size_t)NW * PD * 2);
  ushort* Hb     = (ushort*)take((size_t)NW * PD * 2);
  ushort* w1b    = (ushort*)take((size_t)PD * PD * 2);
  ushort* w2b    = (ushort*)take((size_t)PD * PD * 2);
  ushort* w3b    = (ushort*)take((size_t)PD * PD * 2);
  ushort* mw1b   = (ushort*)take((size_t)PD * PD * 2);
  ushort* mw2b   = (ushort*)take((size_t)PD * PD * 2);
  int* curA = cursors;
  int* curX = cursors + NW;
  // doc-stage buffers alias Hb (word H3 is dead once res_ln has produced S in Tb)
  ushort* docHb = Hb;
  ushort* h1b   = Hb + (size_t)ND * PD;
  ushort* h2b   = Hb + (size_t)2 * ND * PD;  // stride 160

  // ---- fused CSR build (A and X) ----
  hipMemsetAsync(cursors, 0, (size_t)(NW + ND) * 4, stream);
  dim3 gh(cdiv(NNZA, 256), 2);
  k_hist2<<<gh, 256, 0, stream>>>(a_rows, x_rows, curA, curX);
  dim3 gb(NBA, 2);
  k_bsum2<<<gb, 1024, 0, stream>>>(curA, curX, bsA, bsX);
  k_scan_small2<<<1, 128, 0, stream>>>(bsA, bsX, a_rp, x_rp);
  k_scan_apply2<<<gb, 1024, 0, stream>>>(curA, curX, bsA, bsX, a_rp, x_rp, curA, curX);
  // ---- converts (independent of scatters) ----
  dim3 gp(cdiv(NW * 40, 256), 6);
  k_prep<<<gp, 256, 0, stream>>>(emb, embb, w1, w2, w3, m_w1, m_w2,
                                 w1b, w2b, w3b, mw1b, mw2b);
  // ---- range-split scatters: active write region stays L2-resident per launch ----
  dim3 gs(cdiv((NNZA + 3) >> 2, 256), 2);
  k_scat2<<<gs, 256, 0, stream>>>(a_rows, a_cols, a_vals, x_rows, x_cols, x_vals,
                                  curA, curX, a_iv, x_iv, 0, NW / 2, 0, ND / 2);
  k_scat2<<<gs, 256, 0, stream>>>(a_rows, a_cols, a_vals, x_rows, x_cols, x_vals,
                                  curA, curX, a_iv, x_iv, NW / 2, NW, ND / 2, ND);

  // ---- word GCN ----
  dim3 gg(2, cdiv(NW, 128));
  k_spmm_b<<<cdiv(NW, 4), 256, 0, stream>>>(a_rp, a_iv, (const uint*)embb, (uint*)Tb, NW);
  k_mgemm<<<gg, 256, 0, stream>>>(Tb, w1b, nullptr, nullptr, nullptr, Hb, NW, DIM, PD, 1);
  k_spmm_b<<<cdiv(NW, 4), 256, 0, stream>>>(a_rp, a_iv, (const uint*)Hb, (uint*)Tb, NW);
  k_mgemm<<<gg, 256, 0, stream>>>(Tb, w2b, nullptr, nullptr, nullptr, Hb, NW, DIM, PD, 1);
  k_spmm_b<<<cdiv(NW, 4), 256, 0, stream>>>(a_rp, a_iv, (const uint*)Hb, (uint*)Tb, NW);
  k_mgemm<<<gg, 256, 0, stream>>>(Tb, w3b, nullptr, nullptr, nullptr, Hb, NW, DIM, PD, 1);
  // ---- residual + LN (S = LN + emb fused into Tb; emb read as bf16) ----
  k_res_ln<<<cdiv(NW, 4), 256, 0, stream>>>((const uint*)embb, (const uint*)Hb, ln_g, ln_b, (uint*)Tb);
  // ---- doc aggregation (single SpMM over summed matrix) ----
  k_spmm_b<<<cdiv(ND, 4), 256, 0, stream>>>(x_rp, x_iv, (const uint*)Tb, (uint*)docHb, ND);
  // ---- MLP head ----
  dim3 g1(2, cdiv(ND, 128));
  k_mgemm<<<g1, 256, 0, stream>>>(docHb, mw1b, m_b1, bn1_g, bn1_b, h1b, ND, DIM, PD, 1);
  dim3 g2(1, cdiv(ND, 128));
  k_mgemm<<<g2, 256, 0, stream>>>(h1b, mw2b, m_b2, bn2_g, bn2_b, h2b, ND, DIM2, 160, 1);
  k_clf<<<cdiv(ND, 4), 256, 0, stream>>>((const uint*)h2b, clf_w, clf_b, out);
}

// Round 15
// 502.277 us; speedup vs baseline: 1.0169x; 1.0169x over previous
//
#include <hip/hip_runtime.h>

#define NW 30000
#define ND 8192
#define DIM 300
#define DIM2 150
#define NNZA 600000
#define NNZX 524288
#define PD 320            // padded feature stride (bf16 elems)
#define PD_U 160          // padded stride in uint (2 bf16 each)
#define NBA 30            // cdiv(NW,1024)
#define NBX 8             // cdiv(ND,1024)
#define BN_SCALE 0.99999500003749971f

typedef unsigned int uint;
typedef unsigned short ushort;
typedef __attribute__((ext_vector_type(8))) short bf16x8;
typedef __attribute__((ext_vector_type(4))) float f32x4;
typedef __attribute__((ext_vector_type(4))) uint uint4v;

static inline int cdiv(int a, int b){ return (a + b - 1) / b; }

__device__ __forceinline__ float b2f_lo(uint u){ return __builtin_bit_cast(float, u << 16); }
__device__ __forceinline__ float b2f_hi(uint u){ return __builtin_bit_cast(float, u & 0xffff0000u); }
__device__ __forceinline__ ushort f2b(float f){
  uint u = __builtin_bit_cast(uint, f);
  u += 0x7fffu + ((u >> 16) & 1u);
  return (ushort)(u >> 16);
}
__device__ __forceinline__ uint packb(float x, float y){
  return (uint)f2b(x) | ((uint)f2b(y) << 16);
}

// ---------------- CSR build (A and X fused via blockIdx.y) ----------------
__global__ void k_hist2(const int* __restrict__ ra, const int* __restrict__ rx,
                        int* __restrict__ cntA, int* __restrict__ cntX){
  int i = blockIdx.x * blockDim.x + threadIdx.x;
  if (blockIdx.y == 0){
    if (i < NNZA) atomicAdd(&cntA[ra[i]], 1);
  } else {
    if (i < NNZX) atomicAdd(&cntX[rx[i]], 1);
  }
}

__global__ __launch_bounds__(1024) void k_bsum2(const int* __restrict__ cntA, const int* __restrict__ cntX,
                                                int* __restrict__ bsA, int* __restrict__ bsX){
  __shared__ int sd[1024];
  const int* cnt; int n; int* bs;
  if (blockIdx.y == 0){ cnt = cntA; n = NW; bs = bsA; }
  else                { cnt = cntX; n = ND; bs = bsX; }
  int t = threadIdx.x;
  int i = blockIdx.x * 1024 + t;
  sd[t] = (i < n) ? cnt[i] : 0;
  __syncthreads();
  #pragma unroll
  for (int o = 512; o > 0; o >>= 1){
    if (t < o) sd[t] += sd[t + o];
    __syncthreads();
  }
  if (t == 0) bs[blockIdx.x] = sd[0];
}

// one block, 128 threads: wave 0 scans A block-sums, wave 1 scans X block-sums
__global__ __launch_bounds__(128) void k_scan_small2(int* __restrict__ bsA, int* __restrict__ bsX,
                                                     int* __restrict__ a_rp, int* __restrict__ x_rp){
  int w = threadIdx.x >> 6, lane = threadIdx.x & 63;
  int* bs = w ? bsX : bsA;
  int nb  = w ? NBX : NBA;
  int* rp = w ? x_rp : a_rp;
  int n   = w ? ND : NW;
  int orig = (lane < nb) ? bs[lane] : 0;
  int v = orig;
  #pragma unroll
  for (int o = 1; o < 64; o <<= 1){
    int x = __shfl_up(v, o);
    if (lane >= o) v += x;
  }
  if (lane < nb) bs[lane] = v - orig;
  if (lane == nb - 1) rp[n] = v;
}

// per-block scan + offset; writes BOTH rp and the scatter cursor
__global__ __launch_bounds__(1024) void k_scan_apply2(const int* __restrict__ cntA, const int* __restrict__ cntX,
        const int* __restrict__ bsA, const int* __restrict__ bsX,
        int* __restrict__ a_rp, int* __restrict__ x_rp,
        int* __restrict__ curA, int* __restrict__ curX){
  __shared__ int sd[1024];
  const int* cnt; const int* bs; int n; int* rp; int* cur;
  if (blockIdx.y == 0){ cnt = cntA; bs = bsA; n = NW; rp = a_rp; cur = curA; }
  else                { cnt = cntX; bs = bsX; n = ND; rp = x_rp; cur = curX; }
  int t = threadIdx.x;
  int i = blockIdx.x * 1024 + t;
  int v = (i < n) ? cnt[i] : 0;
  sd[t] = v;
  __syncthreads();
  for (int o = 1; o < 1024; o <<= 1){
    int x = (t >= o) ? sd[t - o] : 0;
    __syncthreads();
    sd[t] += x;
    __syncthreads();
  }
  if (i < n){
    int start = bs[blockIdx.x] + sd[t] - v;
    rp[i] = start;
    cur[i] = start;
  }
}

// ---- fused prep: scatter A, scatter X (interleaved col/val, scalar stores), emb + 5 weights ----
__global__ void k_prep(const int* __restrict__ a_rows, const int* __restrict__ a_cols, const float* __restrict__ a_vals,
                       const int* __restrict__ x_rows, const int* __restrict__ x_cols, const float* __restrict__ x_vals,
                       int* __restrict__ curA, int* __restrict__ curX,
                       int* __restrict__ a_iv, int* __restrict__ x_iv,
                       const float* __restrict__ emb, ushort* __restrict__ embb,
                       const float* __restrict__ w1, const float* __restrict__ w2, const float* __restrict__ w3,
                       const float* __restrict__ mw1, const float* __restrict__ mw2,
                       ushort* __restrict__ w1b, ushort* __restrict__ w2b, ushort* __restrict__ w3b,
                       ushort* __restrict__ mw1b, ushort* __restrict__ mw2b){
  int y = blockIdx.y;
  int gi = blockIdx.x * blockDim.x + threadIdx.x;
  if (y == 0){
    if (gi < NNZA){
      int r = a_rows[gi];
      int p = atomicAdd(&curA[r], 1);
      a_iv[2 * p]     = a_cols[gi];                          // adjacent 4B stores ->
      a_iv[2 * p + 1] = __builtin_bit_cast(int, a_vals[gi]); // one dirty line per nnz
    }
  } else if (y == 1){
    if (gi < NNZX){
      int r = x_rows[gi];
      int p = atomicAdd(&curX[r], 1);
      x_iv[2 * p]     = x_cols[gi];
      x_iv[2 * p + 1] = __builtin_bit_cast(int, x_vals[gi]);
    }
  } else if (y == 2){
    if (gi < NW * 40){
      int r = gi / 40;
      int c = (gi - r * 40) << 3;
      float x[8];
      #pragma unroll
      for (int j = 0; j < 8; ++j)
        x[j] = (c + j < DIM) ? emb[(size_t)r * DIM + c + j] : 0.f;
      uint4v o;
      o.x = packb(x[0], x[1]); o.y = packb(x[2], x[3]);
      o.z = packb(x[4], x[5]); o.w = packb(x[6], x[7]);
      *(uint4v*)(embb + (size_t)r * PD + c) = o;
    }
  } else {
    if (gi < PD * 40){
      int r = gi / 40;
      int c = (gi - r * 40) << 3;
      const float* src; ushort* dst; int srows;
      if      (y == 3){ src = w1;  dst = w1b;  srows = DIM;  }
      else if (y == 4){ src = w2;  dst = w2b;  srows = DIM;  }
      else if (y == 5){ src = w3;  dst = w3b;  srows = DIM;  }
      else if (y == 6){ src = mw1; dst = mw1b; srows = DIM;  }
      else            { src = mw2; dst = mw2b; srows = DIM2; }
      float x[8];
      #pragma unroll
      for (int j = 0; j < 8; ++j)
        x[j] = (r < srows && c + j < DIM) ? src[(size_t)r * DIM + c + j] : 0.f;
      uint4v o;
      o.x = packb(x[0], x[1]); o.y = packb(x[2], x[3]);
      o.z = packb(x[4], x[5]); o.w = packb(x[6], x[7]);
      *(uint4v*)(dst + (size_t)r * PD + c) = o;
    }
  }
}

// ---------------- SpMM over bf16 table: one wave per row, unroll-4, interleaved iv ------------
__global__ __launch_bounds__(256) void k_spmm_b(const int* __restrict__ rp, const int* __restrict__ iv,
        const uint* __restrict__ Hb, uint* __restrict__ Ob, int nrows){
  int wid = (blockIdx.x * blockDim.x + threadIdx.x) >> 6;
  int lane = threadIdx.x & 63;
  if (wid >= nrows) return;
  int s = rp[wid], e = rp[wid + 1];
  const bool half = lane < 32;
  float acc[4][6] = {};
  int k = s;
  for (; k + 4 <= e; k += 4){
    #pragma unroll
    for (int j = 0; j < 4; ++j){
      int c   = iv[2 * (k + j)];
      float v = __builtin_bit_cast(float, iv[2 * (k + j) + 1]);
      const uint* p = Hb + (size_t)c * PD_U;
      uint u0 = p[lane], u1 = p[lane + 64];
      uint u2 = half ? p[lane + 128] : 0;
      acc[j][0] = fmaf(v, b2f_lo(u0), acc[j][0]);
      acc[j][1] = fmaf(v, b2f_hi(u0), acc[j][1]);
      acc[j][2] = fmaf(v, b2f_lo(u1), acc[j][2]);
      acc[j][3] = fmaf(v, b2f_hi(u1), acc[j][3]);
      acc[j][4] = fmaf(v, b2f_lo(u2), acc[j][4]);
      acc[j][5] = fmaf(v, b2f_hi(u2), acc[j][5]);
    }
  }
  for (; k < e; ++k){
    int c   = iv[2 * k];
    float v = __builtin_bit_cast(float, iv[2 * k + 1]);
    const uint* p = Hb + (size_t)c * PD_U;
    uint u0 = p[lane], u1 = p[lane + 64];
    uint u2 = half ? p[lane + 128] : 0;
    acc[0][0] = fmaf(v, b2f_lo(u0), acc[0][0]);
    acc[0][1] = fmaf(v, b2f_hi(u0), acc[0][1]);
    acc[0][2] = fmaf(v, b2f_lo(u1), acc[0][2]);
    acc[0][3] = fmaf(v, b2f_hi(u1), acc[0][3]);
    acc[0][4] = fmaf(v, b2f_lo(u2), acc[0][4]);
    acc[0][5] = fmaf(v, b2f_hi(u2), acc[0][5]);
  }
  #pragma unroll
  for (int d = 0; d < 6; ++d)
    acc[0][d] += (acc[1][d] + acc[2][d]) + acc[3][d];
  uint* o = Ob + (size_t)wid * PD_U;
  o[lane] = packb(acc[0][0], acc[0][1]);
  o[lane + 64] = packb(acc[0][2], acc[0][3]);
  if (half) o[lane + 128] = packb(acc[0][4], acc[0][5]);
}

// ---------------- MFMA GEMM: C[M,Nvalid] = act(A[M,320]bf16 @ B[n][k]bf16^T) (proven) ------
// BM=128, BN=160, BK=64, 4 waves (2x2), wave tile 64x80 (4x5 16x16 frags).
__global__ __launch_bounds__(256) void k_mgemm(const ushort* __restrict__ A, const ushort* __restrict__ B,
        const float* __restrict__ bias, const float* __restrict__ bng, const float* __restrict__ bnb,
        ushort* __restrict__ C, int M, int Nvalid, int ldc, int relu){
  __shared__ ushort As[128][72];
  __shared__ ushort Bs[160][72];
  const int t = threadIdx.x;
  const int wid = t >> 6, lane = t & 63;
  const int bm = blockIdx.y << 7;
  const int bn = blockIdx.x * 160;
  const int wm = (wid >> 1) << 6;   // 0 / 64
  const int wn = (wid & 1) * 80;    // 0 / 80
  const int r16 = lane & 15;
  const int h8 = (lane >> 4) << 3;  // k-offset within 32
  f32x4 acc[4][5] = {};
  for (int k0 = 0; k0 < PD; k0 += 64){
    #pragma unroll
    for (int i = 0; i < 4; ++i){
      int q = t + (i << 8);
      int r = q >> 3, c = (q & 7) << 3;
      int gm = bm + r; if (gm >= M) gm = M - 1;
      *(bf16x8*)(&As[r][c]) = *(const bf16x8*)(A + (size_t)gm * PD + k0 + c);
    }
    #pragma unroll
    for (int i = 0; i < 5; ++i){
      int q = t + (i << 8);
      int r = q >> 3, c = (q & 7) << 3;
      *(bf16x8*)(&Bs[r][c]) = *(const bf16x8*)(B + (size_t)(bn + r) * PD + k0 + c);
    }
    __syncthreads();
    #pragma unroll
    for (int kk = 0; kk < 2; ++kk){
      bf16x8 af[4], bfr[5];
      #pragma unroll
      for (int m = 0; m < 4; ++m)
        af[m] = *(const bf16x8*)(&As[wm + m * 16 + r16][kk * 32 + h8]);
      #pragma unroll
      for (int n = 0; n < 5; ++n)
        bfr[n] = *(const bf16x8*)(&Bs[wn + n * 16 + r16][kk * 32 + h8]);
      #pragma unroll
      for (int m = 0; m < 4; ++m)
        #pragma unroll
        for (int n = 0; n < 5; ++n)
          acc[m][n] = __builtin_amdgcn_mfma_f32_16x16x32_bf16(af[m], bfr[n], acc[m][n], 0, 0, 0);
    }
    __syncthreads();
  }
  const int cr = (lane >> 4) << 2;
  #pragma unroll
  for (int m = 0; m < 4; ++m){
    #pragma unroll
    for (int n = 0; n < 5; ++n){
      int col = bn + wn + n * 16 + r16;
      #pragma unroll
      for (int j = 0; j < 4; ++j){
        int row = bm + wm + m * 16 + cr + j;
        if (row >= M) continue;
        float v = acc[m][n][j];
        if (col < Nvalid){
          if (bias) v += bias[col];
          if (bng)  v = v * (bng[col] * BN_SCALE) + bnb[col];
          if (relu) v = fmaxf(v, 0.f);
        } else v = 0.f;
        C[(size_t)row * ldc + col] = f2b(v);
      }
    }
  }
}

// ---------------- residual + LayerNorm; S = LN(0.3*emb + 0.7*H) + emb (bf16 emb input) ------
__global__ __launch_bounds__(256) void k_res_ln(const uint* __restrict__ E, const uint* __restrict__ Hb,
        const float* __restrict__ g, const float* __restrict__ bb, uint* __restrict__ S){
  int row = blockIdx.x * 4 + (threadIdx.x >> 6);
  int lane = threadIdx.x & 63;
  if (row >= NW) return;
  const uint* e = E + (size_t)row * PD_U;
  const uint* h = Hb + (size_t)row * PD_U;
  float x[6], ev[6];
  float sum = 0.f, sq = 0.f;
  #pragma unroll
  for (int j = 0; j < 3; ++j){
    int i = lane + j * 64;
    float e0 = 0.f, e1 = 0.f, h0 = 0.f, h1 = 0.f;
    if (i < 150){
      uint u = h[i];
      uint ue = e[i];
      h0 = b2f_lo(u);  h1 = b2f_hi(u);
      e0 = b2f_lo(ue); e1 = b2f_hi(ue);
    }
    float v0 = 0.3f * e0 + 0.7f * h0;
    float v1 = 0.3f * e1 + 0.7f * h1;
    if (i >= 150){ v0 = 0.f; v1 = 0.f; }
    x[2*j] = v0; x[2*j+1] = v1; ev[2*j] = e0; ev[2*j+1] = e1;
    sum += v0 + v1; sq += v0 * v0 + v1 * v1;
  }
  #pragma unroll
  for (int o = 32; o > 0; o >>= 1){ sum += __shfl_down(sum, o); sq += __shfl_down(sq, o); }
  sum = __shfl(sum, 0); sq = __shfl(sq, 0);
  const float inv = 1.f / (float)DIM;
  float mu = sum * inv;
  float var = sq * inv - mu * mu;
  float rs = rsqrtf(var + 1e-5f);
  uint* o = S + (size_t)row * PD_U;
  #pragma unroll
  for (int j = 0; j < 3; ++j){
    int i = lane + j * 64;
    if (i >= PD_U) continue;
    uint w = 0;
    if (i < 150){
      float r0 = (x[2*j]   - mu) * rs * g[2*i]   + bb[2*i]   + ev[2*j];
      float r1 = (x[2*j+1] - mu) * rs * g[2*i+1] + bb[2*i+1] + ev[2*j+1];
      w = packb(r0, r1);
    }
    o[i] = w;
  }
}

// ---------------- classifier: wave per row; 64 lanes cover 75 uints (11 lanes take 2) -------
__global__ __launch_bounds__(256) void k_clf(const uint* __restrict__ h2, const float* __restrict__ w,
                      const float* __restrict__ bias, float* __restrict__ out){
  int row = blockIdx.x * 4 + (threadIdx.x >> 6);
  int lane = threadIdx.x & 63;
  if (row >= ND) return;
  float s0, s1;
  {
    uint u = h2[(size_t)row * 80 + lane];       // uints 0..63 (cols 0..127)
    float h0 = b2f_lo(u), h1 = b2f_hi(u);
    int k = 2 * lane;
    s0 = h0 * w[k] + h1 * w[k + 1];
    s1 = h0 * w[DIM2 + k] + h1 * w[DIM2 + k + 1];
  }
  if (lane < 11){
    uint u = h2[(size_t)row * 80 + 64 + lane];  // uints 64..74 (cols 128..149)
    float h0 = b2f_lo(u), h1 = b2f_hi(u);
    int k = 2 * (64 + lane);
    s0 += h0 * w[k] + h1 * w[k + 1];
    s1 += h0 * w[DIM2 + k] + h1 * w[DIM2 + k + 1];
  }
  #pragma unroll
  for (int o = 32; o > 0; o >>= 1){
    s0 += __shfl_down(s0, o);
    s1 += __shfl_down(s1, o);
  }
  if (lane == 0){
    out[row * 2]     = s0 + bias[0];
    out[row * 2 + 1] = s1 + bias[1];
  }
}

extern "C" void kernel_launch(void* const* d_in, const int* in_sizes, int n_in,
                              void* d_out, int out_size, void* d_ws, size_t ws_size,
                              hipStream_t stream){
  const int*   a_rows = (const int*)  d_in[0];
  const int*   a_cols = (const int*)  d_in[1];
  const float* a_vals = (const float*)d_in[2];
  const int*   x_rows = (const int*)  d_in[3];
  const int*   x_cols = (const int*)  d_in[4];
  const float* x_vals = (const float*)d_in[5];
  const float* emb    = (const float*)d_in[6];
  const float* w1     = (const float*)d_in[7];
  const float* w2     = (const float*)d_in[8];
  const float* w3     = (const float*)d_in[9];
  const float* ln_g   = (const float*)d_in[10];
  const float* ln_b   = (const float*)d_in[11];
  const float* m_w1   = (const float*)d_in[12];
  const float* m_b1   = (const float*)d_in[13];
  const float* bn1_g  = (const float*)d_in[14];
  const float* bn1_b  = (const float*)d_in[15];
  const float* m_w2   = (const float*)d_in[16];
  const float* m_b2   = (const float*)d_in[17];
  const float* bn2_g  = (const float*)d_in[18];
  const float* bn2_b  = (const float*)d_in[19];
  const float* clf_w  = (const float*)d_in[20];
  const float* clf_b  = (const float*)d_in[21];
  float* out = (float*)d_out;

  char* ws = (char*)d_ws;
  size_t off = 0;
  auto take = [&](size_t nbytes)->void*{
    void* p = ws + off;
    off += (nbytes + 255) & ~(size_t)255;
    return p;
  };
  int*    a_rp   = (int*)   take((NW + 1) * 4);
  int*    a_iv   = (int*)   take((size_t)NNZA * 8);
  int*    x_rp   = (int*)   take((ND + 1) * 4);
  int*    x_iv   = (int*)   take((size_t)NNZX * 8);
  int*    cursors= (int*)   take((size_t)(NW + ND) * 4);
  int*    bsA    = (int*)   take(64 * 4);
  int*    bsX    = (int*)   take(64 * 4);
  ushort* embb   = (ushort*)take((size_t)NW * PD * 2);
  ushort* Tb     = (ushort*)take((size_t)NW * PD * 2);
  ushort* Hb     = (ushort*)take((size_t)NW * PD * 2);
  ushort* w1b    = (ushort*)take((size_t)PD * PD * 2);
  ushort* w2b    = (ushort*)take((size_t)PD * PD * 2);
  ushort* w3b    = (ushort*)take((size_t)PD * PD * 2);
  ushort* mw1b   = (ushort*)take((size_t)PD * PD * 2);
  ushort* mw2b   = (ushort*)take((size_t)PD * PD * 2);
  int* curA = cursors;
  int* curX = cursors + NW;
  // doc-stage buffers alias Hb (word H3 is dead once res_ln has produced S in Tb)
  ushort* docHb = Hb;
  ushort* h1b   = Hb + (size_t)ND * PD;
  ushort* h2b   = Hb + (size_t)2 * ND * PD;  // stride 160

  // ---- fused CSR build (A and X) ----
  hipMemsetAsync(cursors, 0, (size_t)(NW + ND) * 4, stream);
  dim3 gh(cdiv(NNZA, 256), 2);
  k_hist2<<<gh, 256, 0, stream>>>(a_rows, x_rows, curA, curX);
  dim3 gb(NBA, 2);
  k_bsum2<<<gb, 1024, 0, stream>>>(curA, curX, bsA, bsX);
  k_scan_small2<<<1, 128, 0, stream>>>(bsA, bsX, a_rp, x_rp);
  k_scan_apply2<<<gb, 1024, 0, stream>>>(curA, curX, bsA, bsX, a_rp, x_rp, curA, curX);
  // ---- fused prep: interleaved scatters + all bf16 converts ----
  dim3 gp(cdiv(NW * 40, 256), 8);
  k_prep<<<gp, 256, 0, stream>>>(a_rows, a_cols, a_vals, x_rows, x_cols, x_vals,
                                 curA, curX, a_iv, x_iv,
                                 emb, embb, w1, w2, w3, m_w1, m_w2,
                                 w1b, w2b, w3b, mw1b, mw2b);

  // ---- word GCN ----
  dim3 gg(2, cdiv(NW, 128));
  k_spmm_b<<<cdiv(NW, 4), 256, 0, stream>>>(a_rp, a_iv, (const uint*)embb, (uint*)Tb, NW);
  k_mgemm<<<gg, 256, 0, stream>>>(Tb, w1b, nullptr, nullptr, nullptr, Hb, NW, DIM, PD, 1);
  k_spmm_b<<<cdiv(NW, 4), 256, 0, stream>>>(a_rp, a_iv, (const uint*)Hb, (uint*)Tb, NW);
  k_mgemm<<<gg, 256, 0, stream>>>(Tb, w2b, nullptr, nullptr, nullptr, Hb, NW, DIM, PD, 1);
  k_spmm_b<<<cdiv(NW, 4), 256, 0, stream>>>(a_rp, a_iv, (const uint*)Hb, (uint*)Tb, NW);
  k_mgemm<<<gg, 256, 0, stream>>>(Tb, w3b, nullptr, nullptr, nullptr, Hb, NW, DIM, PD, 1);
  // ---- residual + LN (S = LN + emb fused into Tb; emb read as bf16) ----
  k_res_ln<<<cdiv(NW, 4), 256, 0, stream>>>((const uint*)embb, (const uint*)Hb, ln_g, ln_b, (uint*)Tb);
  // ---- doc aggregation (single SpMM over summed matrix) ----
  k_spmm_b<<<cdiv(ND, 4), 256, 0, stream>>>(x_rp, x_iv, (const uint*)Tb, (uint*)docHb, ND);
  // ---- MLP head ----
  dim3 g1(2, cdiv(ND, 128));
  k_mgemm<<<g1, 256, 0, stream>>>(docHb, mw1b, m_b1, bn1_g, bn1_b, h1b, ND, DIM, PD, 1);
  dim3 g2(1, cdiv(ND, 128));
  k_mgemm<<<g2, 256, 0, stream>>>(h1b, mw2b, m_b2, bn2_g, bn2_b, h2b, ND, DIM2, 160, 1);
  k_clf<<<cdiv(ND, 4), 256, 0, stream>>>((const uint*)h2b, clf_w, clf_b, out);
}